// Round 5
// baseline (34.357 us; speedup 1.0000x reference)
//
#include <hip/hip_runtime.h>

// ColorTransform — R5 MEASUREMENT ROUND.
// Two identical full passes in ONE dispatch (idempotent rewrite of d_out) to
// push our kernel's duration above the harness's ~40us fill dispatches so it
// appears in rocprof top-5 and we finally see ITS counters (FETCH/WRITE/
// VALUBusy/Occupancy/VGPR). Structure per pass = R1's best (4px/thread,
// 2048 blocks, plain grid-stride).
// Interpretation: FETCH~100MB => truly HBM-bound (little headroom left);
// FETCH<<100MB => L3 absorbs, kernel is latency/cache-path bound => headroom.

constexpr int HW = 512 * 512;          // pixels per (b, c) plane
constexpr int LOG2_HW = 18;

typedef float v4f __attribute__((ext_vector_type(4)));

__device__ __forceinline__ float rfl(float v) {
    return __uint_as_float(__builtin_amdgcn_readfirstlane(__float_as_uint(v)));
}

__global__ __launch_bounds__(256) void ct_probe2x(
    const float* __restrict__ x, const float* __restrict__ wgt,
    const float* __restrict__ bias, float* __restrict__ out, int ngroups)
{
    float w[57];
#pragma unroll
    for (int i = 0; i < 57; ++i) w[i] = rfl(wgt[i]);
    const float b0 = rfl(bias[0]);
    const float b1 = rfl(bias[1]);
    const float b2 = rfl(bias[2]);

    const int tid = blockIdx.x * blockDim.x + threadIdx.x;
    const int nthreads = gridDim.x * blockDim.x;

    for (int pass = 0; pass < 2; ++pass) {      // pass 1 rewrites same values
        for (int g = tid; g < ngroups; g += nthreads) {
            const int p  = g << 2;               // 4 px / group
            const int b  = p >> LOG2_HW;
            const int hw = p & (HW - 1);

            const float* base = x + (size_t)b * 3 * HW + hw;
            v4f va = *reinterpret_cast<const v4f*>(base);
            v4f vb = *reinterpret_cast<const v4f*>(base + HW);
            v4f vc = *reinterpret_cast<const v4f*>(base + 2 * HW);

            v4f o0, o1, o2;
#pragma unroll
            for (int j = 0; j < 4; ++j) {
                const float a = va[j], bch = vb[j], c = vc[j];
                float f[19];
                f[0]  = a;          f[1]  = bch;        f[2]  = c;
                f[3]  = a * a;      f[4]  = a * bch;    f[5]  = a * c;
                f[6]  = bch * bch;  f[7]  = bch * c;    f[8]  = c * c;
                f[9]  = a * f[3];   f[10] = a * f[4];   f[11] = a * f[5];
                f[12] = a * f[6];   f[13] = a * f[7];   f[14] = a * f[8];
                f[15] = bch * f[6]; f[16] = bch * f[7]; f[17] = bch * f[8];
                f[18] = c * f[8];

                float s0 = b0, s1 = b1, s2 = b2;
#pragma unroll
                for (int k = 0; k < 19; ++k) {
                    s0 = fmaf(f[k], w[3 * k + 0], s0);
                    s1 = fmaf(f[k], w[3 * k + 1], s1);
                    s2 = fmaf(f[k], w[3 * k + 2], s2);
                }
                o0[j] = s0; o1[j] = s1; o2[j] = s2;
            }

            float* obase = out + (size_t)b * 3 * HW + hw;
            *reinterpret_cast<v4f*>(obase)          = o0;
            *reinterpret_cast<v4f*>(obase + HW)     = o1;
            *reinterpret_cast<v4f*>(obase + 2 * HW) = o2;
        }
    }
}

extern "C" void kernel_launch(void* const* d_in, const int* in_sizes, int n_in,
                              void* d_out, int out_size, void* d_ws, size_t ws_size,
                              hipStream_t stream) {
    const float* x    = (const float*)d_in[0];   // [16,3,512,512]
    const float* wgt  = (const float*)d_in[1];   // [19,3]
    const float* bias = (const float*)d_in[2];   // [3]
    float* out = (float*)d_out;

    const int npix    = in_sizes[0] / 3;         // 4,194,304
    const int ngroups = npix / 4;
    const int block   = 256;
    const int grid    = 2048;                    // R1's best config
    ct_probe2x<<<grid, block, 0, stream>>>(x, wgt, bias, out, ngroups);
}

// Round 6
// 25.103 us; speedup vs baseline: 1.3686x; 1.3686x over previous
//
#include <hip/hip_runtime.h>

// ColorTransform: per-pixel degree-3 poly expansion (19 monomials of 3 chans)
// + 19->3 linear map. x:[16,3,512,512] f32. out:[16,3,512,512] f32.
//
// R5 probe counters (2-pass, 39.3us): FETCH 40MB (L3 serves most reads),
// WRITE 93MB, VALUBusy ~50% (~10us VALU/pass), warm-pass marginal 17.8us
// => VALU+latency bound, NOT HBM-bound (HBM floor ~11us).
// R6: halve VALU issue via packed fp32 (v_pk_fma_f32/v_pk_mul_f32): compute
// pixel PAIRS as float2 ext-vectors, __builtin_elementwise_fma for the 57-FMA
// chain. Same per-element association order as reference. Config = R1 best
// (4px/thread, 2048 blocks, grid-stride x2, plain loads/stores — nt hurt).

constexpr int HW = 512 * 512;          // pixels per (b, c) plane
constexpr int LOG2_HW = 18;

typedef float v2f __attribute__((ext_vector_type(2)));
typedef float v4f __attribute__((ext_vector_type(4)));

__device__ __forceinline__ float rfl(float v) {
    // Wave-uniform -> SGPR (keeps 57 weights + bias out of VGPR budget).
    return __uint_as_float(__builtin_amdgcn_readfirstlane(__float_as_uint(v)));
}

__device__ __forceinline__ v2f splat2(float s) { return (v2f){s, s}; }

__global__ __launch_bounds__(256) void ct_kernel(
    const float* __restrict__ x, const float* __restrict__ wgt,
    const float* __restrict__ bias, float* __restrict__ out, int ngroups)
{
    float w[57];
#pragma unroll
    for (int i = 0; i < 57; ++i) w[i] = rfl(wgt[i]);
    const float b0 = rfl(bias[0]);
    const float b1 = rfl(bias[1]);
    const float b2 = rfl(bias[2]);

    const int tid = blockIdx.x * blockDim.x + threadIdx.x;
    const int nthreads = gridDim.x * blockDim.x;

    for (int g = tid; g < ngroups; g += nthreads) {
        const int p  = g << 2;               // 4 px / group
        const int b  = p >> LOG2_HW;         // HW = 2^18
        const int hw = p & (HW - 1);

        const float* base = x + (size_t)b * 3 * HW + hw;
        const v4f va = *reinterpret_cast<const v4f*>(base);
        const v4f vb = *reinterpret_cast<const v4f*>(base + HW);
        const v4f vc = *reinterpret_cast<const v4f*>(base + 2 * HW);

        v4f o0, o1, o2;
#pragma unroll
        for (int h = 0; h < 2; ++h) {        // 2 pixel-pairs -> packed f32 ops
            const v2f a  = (v2f){va[2 * h], va[2 * h + 1]};
            const v2f bc = (v2f){vb[2 * h], vb[2 * h + 1]};
            const v2f c  = (v2f){vc[2 * h], vc[2 * h + 1]};

            // 19 monomials, exact reference order & association (per element):
            v2f f[19];
            f[0]  = a;           f[1]  = bc;          f[2]  = c;
            f[3]  = a * a;       f[4]  = a * bc;      f[5]  = a * c;
            f[6]  = bc * bc;     f[7]  = bc * c;      f[8]  = c * c;
            f[9]  = a * f[3];    f[10] = a * f[4];    f[11] = a * f[5];
            f[12] = a * f[6];    f[13] = a * f[7];    f[14] = a * f[8];
            f[15] = bc * f[6];   f[16] = bc * f[7];   f[17] = bc * f[8];
            f[18] = c * f[8];

            v2f s0 = splat2(b0), s1 = splat2(b1), s2 = splat2(b2);
#pragma unroll
            for (int k = 0; k < 19; ++k) {
                s0 = __builtin_elementwise_fma(f[k], splat2(w[3 * k + 0]), s0);
                s1 = __builtin_elementwise_fma(f[k], splat2(w[3 * k + 1]), s1);
                s2 = __builtin_elementwise_fma(f[k], splat2(w[3 * k + 2]), s2);
            }
            o0[2 * h] = s0.x; o0[2 * h + 1] = s0.y;
            o1[2 * h] = s1.x; o1[2 * h + 1] = s1.y;
            o2[2 * h] = s2.x; o2[2 * h + 1] = s2.y;
        }

        float* obase = out + (size_t)b * 3 * HW + hw;
        *reinterpret_cast<v4f*>(obase)          = o0;
        *reinterpret_cast<v4f*>(obase + HW)     = o1;
        *reinterpret_cast<v4f*>(obase + 2 * HW) = o2;
    }
}

extern "C" void kernel_launch(void* const* d_in, const int* in_sizes, int n_in,
                              void* d_out, int out_size, void* d_ws, size_t ws_size,
                              hipStream_t stream) {
    const float* x    = (const float*)d_in[0];   // [16,3,512,512]
    const float* wgt  = (const float*)d_in[1];   // [19,3]
    const float* bias = (const float*)d_in[2];   // [3]
    float* out = (float*)d_out;

    const int npix    = in_sizes[0] / 3;         // 4,194,304
    const int ngroups = npix / 4;                // 4 px per group
    const int block   = 256;
    const int grid    = 2048;                    // grid-stride x2 (R1 best)
    ct_kernel<<<grid, block, 0, stream>>>(x, wgt, bias, out, ngroups);
}

// Round 7
// 20.629 us; speedup vs baseline: 1.6655x; 1.2169x over previous
//
#include <hip/hip_runtime.h>

// ColorTransform: per-pixel degree-3 poly expansion (19 monomials of 3 chans)
// + 19->3 linear map. x:[16,3,512,512] f32 -> out:[16,3,512,512] f32.
//
// Evidence so far: R1 (4px/thread, 2048 blk, grid-stride x2, scalar fma) =
// 21.5us is best. R2 (+nt, one-shot) 24.1; R3 (8px one-shot) 22.2; R4 (1024
// blk pipelined) 25.0; R6 (packed v2f math) 25.1 — all regressed.
// R5 probe: FETCH ~20MB, WRITE ~46MB per pass (3.1 TB/s — NOT BW-bound),
// VALUBusy ~50%, warm-pass 17.8us => latency + VALU co-bound.
// R7: de-confound R2 — pure one-shot, 4096 blocks, 4px/thread, R1's exact
// scalar math, no nt. 16384 waves = 2x CU capacity for latency hiding; no
// grid-stride loop, no bounds check (4096*256 threads == ngroups exactly).

constexpr int HW = 512 * 512;          // pixels per (b, c) plane
constexpr int LOG2_HW = 18;

typedef float v4f __attribute__((ext_vector_type(4)));

__device__ __forceinline__ float rfl(float v) {
    // Wave-uniform -> SGPR (keeps 57 weights + bias out of VGPR budget;
    // v_fma_f32 takes one SGPR operand directly).
    return __uint_as_float(__builtin_amdgcn_readfirstlane(__float_as_uint(v)));
}

__global__ __launch_bounds__(256) void ct_kernel(
    const float* __restrict__ x, const float* __restrict__ wgt,
    const float* __restrict__ bias, float* __restrict__ out)
{
    float w[57];
#pragma unroll
    for (int i = 0; i < 57; ++i) w[i] = rfl(wgt[i]);
    const float b0 = rfl(bias[0]);
    const float b1 = rfl(bias[1]);
    const float b2 = rfl(bias[2]);

    const int g  = blockIdx.x * blockDim.x + threadIdx.x;  // exact: no bound chk
    const int p  = g << 2;               // 4 px / thread
    const int b  = p >> LOG2_HW;         // HW = 2^18
    const int hw = p & (HW - 1);
    const size_t off = (size_t)b * 3 * HW + hw;

    // All 3 loads issued before any compute.
    const float* base = x + off;
    const v4f va = *reinterpret_cast<const v4f*>(base);
    const v4f vb = *reinterpret_cast<const v4f*>(base + HW);
    const v4f vc = *reinterpret_cast<const v4f*>(base + 2 * HW);

    v4f o0, o1, o2;
#pragma unroll
    for (int j = 0; j < 4; ++j) {
        const float a = va[j], bch = vb[j], c = vc[j];
        // 19 monomials, exact reference order & association:
        float f[19];
        f[0]  = a;          f[1]  = bch;        f[2]  = c;
        f[3]  = a * a;      f[4]  = a * bch;    f[5]  = a * c;
        f[6]  = bch * bch;  f[7]  = bch * c;    f[8]  = c * c;
        f[9]  = a * f[3];   f[10] = a * f[4];   f[11] = a * f[5];
        f[12] = a * f[6];   f[13] = a * f[7];   f[14] = a * f[8];
        f[15] = bch * f[6]; f[16] = bch * f[7]; f[17] = bch * f[8];
        f[18] = c * f[8];

        float s0 = b0, s1 = b1, s2 = b2;
#pragma unroll
        for (int k = 0; k < 19; ++k) {
            s0 = fmaf(f[k], w[3 * k + 0], s0);
            s1 = fmaf(f[k], w[3 * k + 1], s1);
            s2 = fmaf(f[k], w[3 * k + 2], s2);
        }
        o0[j] = s0; o1[j] = s1; o2[j] = s2;
    }

    float* obase = out + off;
    *reinterpret_cast<v4f*>(obase)          = o0;
    *reinterpret_cast<v4f*>(obase + HW)     = o1;
    *reinterpret_cast<v4f*>(obase + 2 * HW) = o2;
}

extern "C" void kernel_launch(void* const* d_in, const int* in_sizes, int n_in,
                              void* d_out, int out_size, void* d_ws, size_t ws_size,
                              hipStream_t stream) {
    const float* x    = (const float*)d_in[0];   // [16,3,512,512]
    const float* wgt  = (const float*)d_in[1];   // [19,3]
    const float* bias = (const float*)d_in[2];   // [3]
    float* out = (float*)d_out;

    const int npix    = in_sizes[0] / 3;         // 4,194,304
    const int ngroups = npix / 4;                // 1,048,576
    const int block   = 256;
    const int grid    = ngroups / block;         // 4096, exact
    ct_kernel<<<grid, block, 0, stream>>>(x, wgt, bias, out);
}

// Round 8
// 20.547 us; speedup vs baseline: 1.6722x; 1.0040x over previous
//
#include <hip/hip_runtime.h>

// ColorTransform: per-pixel degree-3 poly in (a,b,c) (19 monomials) + 19->3
// linear map. x:[16,3,512,512] f32 -> out:[16,3,512,512] f32.
//
// Evidence: R7 best = 20.6us (one-shot, 4096 blk, 4px/thread, scalar fma).
// R5 probe: FETCH ~20MB/pass (L3-warm reads), WRITE ~46MB, VALUBusy ~50%
// => co-bound VALU-issue + cache latency. nt hints hurt (R2), pk-f32 hurt
// (R6), fewer blocks hurt (R4).
// R8: pure-Horner rewrite — pred_c = P0 + a*(P1 + a*(P2 + a*w9)), each P_i
// nested Horner in b then c. 19 FMA/channel, 57 FMA/px, ZERO muls (was
// 16 mul + 57 FMA = 73 ops). -22% VALU issue. Structure identical to R7.

constexpr int HW = 512 * 512;          // pixels per (b, c) plane
constexpr int LOG2_HW = 18;

typedef float v4f __attribute__((ext_vector_type(4)));

__device__ __forceinline__ float rfl(float v) {
    // Wave-uniform -> SGPR (weights stay out of the VGPR budget; v_fma_f32
    // takes one SGPR operand directly).
    return __uint_as_float(__builtin_amdgcn_readfirstlane(__float_as_uint(v)));
}

__global__ __launch_bounds__(256) void ct_kernel(
    const float* __restrict__ x, const float* __restrict__ wgt,
    const float* __restrict__ bias, float* __restrict__ out)
{
    float w[57];
#pragma unroll
    for (int i = 0; i < 57; ++i) w[i] = rfl(wgt[i]);
    const float bs0 = rfl(bias[0]);
    const float bs1 = rfl(bias[1]);
    const float bs2 = rfl(bias[2]);

    const int g  = blockIdx.x * blockDim.x + threadIdx.x;  // exact grid
    const int p  = g << 2;               // 4 px / thread
    const int b  = p >> LOG2_HW;         // HW = 2^18
    const int hw = p & (HW - 1);
    const size_t off = (size_t)b * 3 * HW + hw;

    const float* base = x + off;
    const v4f va = *reinterpret_cast<const v4f*>(base);
    const v4f vb = *reinterpret_cast<const v4f*>(base + HW);
    const v4f vc = *reinterpret_cast<const v4f*>(base + 2 * HW);

    v4f o0, o1, o2;
#pragma unroll
    for (int j = 0; j < 4; ++j) {
        const float a  = va[j];
        const float bb = vb[j];
        const float c  = vc[j];

#pragma unroll
        for (int ch = 0; ch < 3; ++ch) {
            const float bsc = (ch == 0) ? bs0 : (ch == 1) ? bs1 : bs2;
            // weight for monomial k, channel ch:
            #define W(k) w[3 * (k) + ch]
            // P0 (a^0): bias + w1*b + w2*c + w6*b2 + w7*bc + w8*c2
            //           + w15*b3 + w16*b2c + w17*bc2 + w18*c3
            float B0 = fmaf(c, fmaf(c, fmaf(c, W(18), W(8)), W(2)), bsc);
            float B1 = fmaf(c, fmaf(c, W(17), W(7)), W(1));
            float B2 = fmaf(c, W(16), W(6));
            float P0 = fmaf(bb, fmaf(bb, fmaf(bb, W(15), B2), B1), B0);
            // P1 (a^1): w0 + w4*b + w5*c + w12*b2 + w13*bc + w14*c2
            float C0 = fmaf(c, fmaf(c, W(14), W(5)), W(0));
            float C1 = fmaf(c, W(13), W(4));
            float P1 = fmaf(bb, fmaf(bb, W(12), C1), C0);
            // P2 (a^2): w3 + w10*b + w11*c
            float P2 = fmaf(c, W(11), fmaf(bb, W(10), W(3)));
            // pred = P0 + a*(P1 + a*(P2 + a*w9))
            float t  = fmaf(a, W(9), P2);
            t        = fmaf(a, t, P1);
            t        = fmaf(a, t, P0);
            #undef W
            if (ch == 0) o0[j] = t; else if (ch == 1) o1[j] = t; else o2[j] = t;
        }
    }

    float* obase = out + off;
    *reinterpret_cast<v4f*>(obase)          = o0;
    *reinterpret_cast<v4f*>(obase + HW)     = o1;
    *reinterpret_cast<v4f*>(obase + 2 * HW) = o2;
}

extern "C" void kernel_launch(void* const* d_in, const int* in_sizes, int n_in,
                              void* d_out, int out_size, void* d_ws, size_t ws_size,
                              hipStream_t stream) {
    const float* x    = (const float*)d_in[0];   // [16,3,512,512]
    const float* wgt  = (const float*)d_in[1];   // [19,3]
    const float* bias = (const float*)d_in[2];   // [3]
    float* out = (float*)d_out;

    const int npix    = in_sizes[0] / 3;         // 4,194,304
    const int ngroups = npix / 4;                // 1,048,576
    const int block   = 256;
    const int grid    = ngroups / block;         // 4096, exact
    ct_kernel<<<grid, block, 0, stream>>>(x, wgt, bias, out);
}

// Round 9
// 20.493 us; speedup vs baseline: 1.6765x; 1.0026x over previous
//
#include <hip/hip_runtime.h>

// ColorTransform: per-pixel degree-3 poly in (a,b,c) (19 monomials) + 19->3
// linear map. x:[16,3,512,512] f32 -> out:[16,3,512,512] f32.
//
// Model (R5 probe + R1): fixed dispatch/ramp X ~ 8.6us, per-pass marginal
// M ~ 12.9us vs memory floor ~10.2us (HBM: ~20MB fetch + ~46MB write; rest
// L3-served). VALU cut (Horner, R8) was neutral => latency-bound.
// px/thread trend (one-shot): 8px=22.2, 4px=20.6 -> R9 tries 2px, 8192
// blocks = 32768 waves (4 gens/CU) for max latency hiding. dwordx2 loads,
// still 512B/wave/load = fully coalesced.

constexpr int HW = 512 * 512;          // pixels per (b, c) plane
constexpr int LOG2_HW = 18;

typedef float v2f __attribute__((ext_vector_type(2)));

__device__ __forceinline__ float rfl(float v) {
    // Wave-uniform -> SGPR (weights out of VGPR budget; v_fma_f32 takes one
    // SGPR operand directly).
    return __uint_as_float(__builtin_amdgcn_readfirstlane(__float_as_uint(v)));
}

__global__ __launch_bounds__(256) void ct_kernel(
    const float* __restrict__ x, const float* __restrict__ wgt,
    const float* __restrict__ bias, float* __restrict__ out)
{
    float w[57];
#pragma unroll
    for (int i = 0; i < 57; ++i) w[i] = rfl(wgt[i]);
    const float bs0 = rfl(bias[0]);
    const float bs1 = rfl(bias[1]);
    const float bs2 = rfl(bias[2]);

    const int g  = blockIdx.x * blockDim.x + threadIdx.x;  // exact grid
    const int p  = g << 1;               // 2 px / thread
    const int b  = p >> LOG2_HW;         // HW = 2^18
    const int hw = p & (HW - 1);
    const size_t off = (size_t)b * 3 * HW + hw;

    const float* base = x + off;
    const v2f va = *reinterpret_cast<const v2f*>(base);
    const v2f vb = *reinterpret_cast<const v2f*>(base + HW);
    const v2f vc = *reinterpret_cast<const v2f*>(base + 2 * HW);

    v2f o0, o1, o2;
#pragma unroll
    for (int j = 0; j < 2; ++j) {
        const float a  = va[j];
        const float bb = vb[j];
        const float c  = vc[j];

#pragma unroll
        for (int ch = 0; ch < 3; ++ch) {
            const float bsc = (ch == 0) ? bs0 : (ch == 1) ? bs1 : bs2;
            #define W(k) w[3 * (k) + ch]
            // Horner: pred = P0 + a*(P1 + a*(P2 + a*w9)); P_i nested in b,c.
            float B0 = fmaf(c, fmaf(c, fmaf(c, W(18), W(8)), W(2)), bsc);
            float B1 = fmaf(c, fmaf(c, W(17), W(7)), W(1));
            float B2 = fmaf(c, W(16), W(6));
            float P0 = fmaf(bb, fmaf(bb, fmaf(bb, W(15), B2), B1), B0);
            float C0 = fmaf(c, fmaf(c, W(14), W(5)), W(0));
            float C1 = fmaf(c, W(13), W(4));
            float P1 = fmaf(bb, fmaf(bb, W(12), C1), C0);
            float P2 = fmaf(c, W(11), fmaf(bb, W(10), W(3)));
            float t  = fmaf(a, W(9), P2);
            t        = fmaf(a, t, P1);
            t        = fmaf(a, t, P0);
            #undef W
            if (ch == 0) o0[j] = t; else if (ch == 1) o1[j] = t; else o2[j] = t;
        }
    }

    float* obase = out + off;
    *reinterpret_cast<v2f*>(obase)          = o0;
    *reinterpret_cast<v2f*>(obase + HW)     = o1;
    *reinterpret_cast<v2f*>(obase + 2 * HW) = o2;
}

extern "C" void kernel_launch(void* const* d_in, const int* in_sizes, int n_in,
                              void* d_out, int out_size, void* d_ws, size_t ws_size,
                              hipStream_t stream) {
    const float* x    = (const float*)d_in[0];   // [16,3,512,512]
    const float* wgt  = (const float*)d_in[1];   // [19,3]
    const float* bias = (const float*)d_in[2];   // [3]
    float* out = (float*)d_out;

    const int npix    = in_sizes[0] / 3;         // 4,194,304
    const int ngroups = npix / 2;                // 2,097,152 (2 px / thread)
    const int block   = 256;
    const int grid    = ngroups / block;         // 8192, exact
    ct_kernel<<<grid, block, 0, stream>>>(x, wgt, bias, out);
}